// Round 3
// baseline (144.634 us; speedup 1.0000x reference)
//
#include <hip/hip_runtime.h>
#include <math.h>

#define N      8192
#define IN_F   256
#define OUT_F  64
#define ALPHA  0.2f
#define LN_EPS 1e-5f
#define KVB    256            // attention columns per chunk
#define NCH    (N / KVB)      // 32 chunks

typedef __attribute__((ext_vector_type(8))) short bf16x8;
typedef __attribute__((ext_vector_type(4))) float f32x4;
typedef __attribute__((ext_vector_type(4))) int   i32x4;

__device__ __forceinline__ float wave_sum(float v) {
#pragma unroll
    for (int off = 32; off >= 1; off >>= 1) v += __shfl_xor(v, off, 64);
    return v;
}

__device__ __forceinline__ short f2bf(float x) {           // RNE float->bf16
    union { float f; unsigned u; } v; v.f = x;
    unsigned r = v.u + 0x7FFF + ((v.u >> 16) & 1);
    return (short)(r >> 16);
}
__device__ __forceinline__ float bf2f(short b) {
    union { unsigned u; float f; } v; v.u = ((unsigned)(unsigned short)b) << 16;
    return v.f;
}

// ---------- Phase A: h = X@W ; store hT_bf16[64][8192]; f = h@a1, g = h@a2 (fp32) ----------
// 256 thr = 4 waves, 8 rows/wave, 32 rows/block, grid 256.
__global__ __launch_bounds__(256) void gat_phaseA(
    const float* __restrict__ input, const float* __restrict__ W,
    const float* __restrict__ a1, const float* __restrict__ a2,
    unsigned short* __restrict__ hT2, float* __restrict__ fv, float* __restrict__ gv)
{
    const int lane = threadIdx.x & 63;
    const int wid  = threadIdx.x >> 6;
    const int blockRow0 = blockIdx.x * 32;
    const int i0 = blockRow0 + wid * 8;

    float hacc[8];
#pragma unroll
    for (int r = 0; r < 8; r++) hacc[r] = 0.f;

    for (int k = 0; k < IN_F; k += 4) {
        const float w0 = W[(k + 0) * OUT_F + lane];
        const float w1 = W[(k + 1) * OUT_F + lane];
        const float w2 = W[(k + 2) * OUT_F + lane];
        const float w3 = W[(k + 3) * OUT_F + lane];
#pragma unroll
        for (int r = 0; r < 8; r++) {
            const float4 iv = *(const float4*)&input[(size_t)(i0 + r) * IN_F + k];
            hacc[r] = fmaf(iv.x, w0, hacc[r]);
            hacc[r] = fmaf(iv.y, w1, hacc[r]);
            hacc[r] = fmaf(iv.z, w2, hacc[r]);
            hacc[r] = fmaf(iv.w, w3, hacc[r]);
        }
    }

    const float a1v = a1[lane];
    const float a2v = a2[lane];

    __shared__ float hsm[32][65];
#pragma unroll
    for (int r = 0; r < 8; r++) {
        hsm[wid * 8 + r][lane] = hacc[r];
        const float fr = wave_sum(hacc[r] * a1v);
        const float gr = wave_sum(hacc[r] * a2v);
        if (lane == 0) { fv[i0 + r] = fr; gv[i0 + r] = gr; }
    }
    __syncthreads();

    // transpose to hT_bf16[f][row], 16B stores
    const int f = threadIdx.x >> 2;            // 0..63
    const int cpart = (threadIdx.x & 3) * 8;   // 0,8,16,24
    union { unsigned short s[8]; int4 v; } pk;
#pragma unroll
    for (int c = 0; c < 8; c++) pk.s[c] = (unsigned short)f2bf(hsm[cpart + c][f]);
    *(int4*)&hT2[(size_t)f * N + blockRow0 + cpart] = pk.v;
}

// ---------- Main: fused masked-exp attention (MFMA) + den + LayerNorm + ELU ----------
// 16 rows/block, 256 thr (4 waves). wave w: producer of k-subtiles {2w,2w+1},
// consumer of feature block w. grid = 512.
__global__ __launch_bounds__(256) void gat_attn(
    const int* __restrict__ adj, const unsigned short* __restrict__ hT2,
    const float* __restrict__ fv, const float* __restrict__ gv,
    const float* __restrict__ gamma, const float* __restrict__ beta,
    float* __restrict__ out)
{
    __shared__ short wlsA[8][64 * 8];     // A-fragments per k-subtile: [ks][lane*8] bf16, 8KB
    __shared__ float lnbuf[16][68];
    __shared__ float denbuf[4][16];

    const int tid  = threadIdx.x;
    const int lane = tid & 63;
    const int wid  = tid >> 6;
    const int n16  = lane & 15;           // A: row, B: feature col, D: feature col
    const int g4   = lane >> 4;           // k-group
    const int rowBase = blockIdx.x * 16;

    const float frow = fv[rowBase + n16];

    f32x4 acc = {0.f, 0.f, 0.f, 0.f};
    float dp = 0.f;

    i32x4  adjA[4], adjB[4];
    float4 gA[4],   gB[4];

#define PREFETCH(JP, ADJ, G) do {                                              \
    const size_t jpo = (size_t)(JP);                                           \
    _Pragma("unroll")                                                          \
    for (int s = 0; s < 2; ++s) {                                              \
        const int ks = wid * 2 + s;                                            \
        const int* ap = adj + (size_t)(rowBase + n16) * N + jpo + ks * 32 + g4 * 8; \
        ADJ[s * 2]     = __builtin_nontemporal_load((const i32x4*)ap);         \
        ADJ[s * 2 + 1] = __builtin_nontemporal_load((const i32x4*)ap + 1);     \
        const float* gp = gv + jpo + ks * 32 + g4 * 8;                         \
        G[s * 2]     = *(const float4*)gp;                                     \
        G[s * 2 + 1] = *((const float4*)gp + 1);                               \
    }                                                                          \
} while (0)

#define STEP(C, ADJ, G, NADJ, NG) do {                                         \
    __syncthreads();  /* consumers of previous wls done */                     \
    const int pc = ((C) + 1 < NCH) ? (C) + 1 : (C);                            \
    PREFETCH((size_t)pc * KVB, NADJ, NG);                                      \
    _Pragma("unroll")                                                          \
    for (int s = 0; s < 2; ++s) {                                              \
        const int ks = wid * 2 + s;                                            \
        bf16x8 pk;                                                             \
        _Pragma("unroll")                                                      \
        for (int e = 0; e < 8; ++e) {                                          \
            const int aval = (e < 4) ? ((const int*)&ADJ[s * 2])[e]            \
                                     : ((const int*)&ADJ[s * 2 + 1])[e - 4];   \
            const float gj = (e < 4) ? ((const float*)&G[s * 2])[e]            \
                                     : ((const float*)&G[s * 2 + 1])[e - 4];   \
            float t = frow + gj;                                               \
            t = fmaxf(t, ALPHA * t);                /* leaky_relu */           \
            const float w = (aval > 0) ? __expf(t) : 0.0f;                     \
            const short wb = f2bf(w);                                          \
            dp += bf2f(wb);                                                    \
            pk[e] = wb;                                                        \
        }                                                                      \
        *(bf16x8*)&wlsA[ks][lane * 8] = pk;                                    \
    }                                                                          \
    __syncthreads();  /* wls visible */                                        \
    {                                                                          \
        const unsigned short* hb = hT2 + (size_t)(wid * 16 + n16) * N          \
                                   + (size_t)(C) * KVB + g4 * 8;               \
        _Pragma("unroll")                                                      \
        for (int ks = 0; ks < 8; ++ks) {                                       \
            bf16x8 a = *(const bf16x8*)&wlsA[ks][lane * 8];                    \
            bf16x8 b = *(const bf16x8*)(hb + ks * 32);                         \
            acc = __builtin_amdgcn_mfma_f32_16x16x32_bf16(a, b, acc, 0, 0, 0); \
        }                                                                      \
    }                                                                          \
} while (0)

    PREFETCH(0, adjA, gA);
    for (int c = 0; c < NCH; c += 2) {
        STEP(c,     adjA, gA, adjB, gB);
        STEP(c + 1, adjB, gB, adjA, gA);
    }
#undef STEP
#undef PREFETCH

    // ---- denominator: lane holds partial for row n16 over its col subset ----
    float dr = dp + __shfl_xor(dp, 16, 64);
    dr += __shfl_xor(dr, 32, 64);
    if (g4 == 0) denbuf[wid][n16] = dr;

    // ---- numerator: D frag -> lnbuf[row][feat] ----
#pragma unroll
    for (int r = 0; r < 4; ++r) lnbuf[g4 * 4 + r][wid * 16 + n16] = acc[r];
    __syncthreads();

    // ---- divide + LayerNorm + ELU: 16 threads per row ----
    const int r = tid >> 4;         // 0..15
    const int q = tid & 15;         // feature quad
    const float den = denbuf[0][r] + denbuf[1][r] + denbuf[2][r] + denbuf[3][r];
    float4 v = *(const float4*)&lnbuf[r][q * 4];
    const float inv = 1.0f / den;
    v.x *= inv; v.y *= inv; v.z *= inv; v.w *= inv;

    float sm = v.x + v.y + v.z + v.w;
#pragma unroll
    for (int o = 1; o < 16; o <<= 1) sm += __shfl_xor(sm, o, 64);
    const float mu = sm * (1.0f / 64.0f);

    const float dx = v.x - mu, dy = v.y - mu, dz = v.z - mu, dw = v.w - mu;
    float ss = dx * dx + dy * dy + dz * dz + dw * dw;
#pragma unroll
    for (int o = 1; o < 16; o <<= 1) ss += __shfl_xor(ss, o, 64);
    const float rs = rsqrtf(ss * (1.0f / 64.0f) + LN_EPS);

    const float4 gm = *(const float4*)&gamma[q * 4];
    const float4 bt = *(const float4*)&beta[q * 4];
    float y0 = dx * rs * gm.x + bt.x;
    float y1 = dy * rs * gm.y + bt.y;
    float y2 = dz * rs * gm.z + bt.z;
    float y3 = dw * rs * gm.w + bt.w;
    y0 = (y0 > 0.f) ? y0 : expm1f(y0);
    y1 = (y1 > 0.f) ? y1 : expm1f(y1);
    y2 = (y2 > 0.f) ? y2 : expm1f(y2);
    y3 = (y3 > 0.f) ? y3 : expm1f(y3);
    *(float4*)&out[(size_t)(rowBase + r) * OUT_F + q * 4] = make_float4(y0, y1, y2, y3);
}

extern "C" void kernel_launch(void* const* d_in, const int* in_sizes, int n_in,
                              void* d_out, int out_size, void* d_ws, size_t ws_size,
                              hipStream_t stream)
{
    const float* input = (const float*)d_in[0];
    const int*   adj   = (const int*)d_in[1];
    const float* W     = (const float*)d_in[2];
    const float* a1    = (const float*)d_in[3];
    const float* a2    = (const float*)d_in[4];
    const float* gamma = (const float*)d_in[5];
    const float* beta  = (const float*)d_in[6];
    float* out = (float*)d_out;

    // workspace: 1 MB hT_bf16 + 32 KB f + 32 KB g  = 1.06 MB total
    unsigned short* hT2 = (unsigned short*)d_ws;
    float* fv = (float*)(hT2 + (size_t)OUT_F * N);
    float* gv = fv + N;

    gat_phaseA<<<N / 32, 256, 0, stream>>>(input, W, a1, a2, hT2, fv, gv);
    gat_attn<<<N / 16, 256, 0, stream>>>(adj, hT2, fv, gv, gamma, beta, out);
}

// Round 4
// 89.219 us; speedup vs baseline: 1.6211x; 1.6211x over previous
//
#include <hip/hip_runtime.h>
#include <math.h>

#define N      8192
#define IN_F   256
#define OUT_F  64
#define ALPHA  0.2f
#define LN_EPS 1e-5f
#define KVB    256            // attention columns per chunk
#define NCH    (N / KVB)      // 32 chunks

typedef __attribute__((ext_vector_type(8))) short bf16x8;
typedef __attribute__((ext_vector_type(4))) short s16x4;
typedef __attribute__((ext_vector_type(4))) float f32x4;
typedef __attribute__((ext_vector_type(4))) int   i32x4;

__device__ __forceinline__ float wave_sum(float v) {
#pragma unroll
    for (int off = 32; off >= 1; off >>= 1) v += __shfl_xor(v, off, 64);
    return v;
}

__device__ __forceinline__ short f2bf(float x) {           // RNE float->bf16
    union { float f; unsigned u; } v; v.f = x;
    unsigned r = v.u + 0x7FFF + ((v.u >> 16) & 1);
    return (short)(r >> 16);
}
__device__ __forceinline__ float bf2f(short b) {
    union { unsigned u; float f; } v; v.u = ((unsigned)(unsigned short)b) << 16;
    return v.f;
}

// ---------- Phase A: h = X@W ; store hB[j>>3][feat][j&7] bf16; f = h@a1, g = h@a2 ----------
// 256 thr = 4 waves, 8 rows/wave, 32 rows/block, grid 256.
__global__ __launch_bounds__(256) void gat_phaseA(
    const float* __restrict__ input, const float* __restrict__ W,
    const float* __restrict__ a1, const float* __restrict__ a2,
    unsigned short* __restrict__ hB, float* __restrict__ fv, float* __restrict__ gv)
{
    const int lane = threadIdx.x & 63;
    const int wid  = threadIdx.x >> 6;
    const int blockRow0 = blockIdx.x * 32;
    const int i0 = blockRow0 + wid * 8;

    float hacc[8];
#pragma unroll
    for (int r = 0; r < 8; r++) hacc[r] = 0.f;

    for (int k = 0; k < IN_F; k += 4) {
        const float w0 = W[(k + 0) * OUT_F + lane];
        const float w1 = W[(k + 1) * OUT_F + lane];
        const float w2 = W[(k + 2) * OUT_F + lane];
        const float w3 = W[(k + 3) * OUT_F + lane];
#pragma unroll
        for (int r = 0; r < 8; r++) {
            const float4 iv = *(const float4*)&input[(size_t)(i0 + r) * IN_F + k];
            hacc[r] = fmaf(iv.x, w0, hacc[r]);
            hacc[r] = fmaf(iv.y, w1, hacc[r]);
            hacc[r] = fmaf(iv.z, w2, hacc[r]);
            hacc[r] = fmaf(iv.w, w3, hacc[r]);
        }
    }

    const float a1v = a1[lane];
    const float a2v = a2[lane];

    __shared__ float hsm[32][65];
#pragma unroll
    for (int r = 0; r < 8; r++) {
        hsm[wid * 8 + r][lane] = hacc[r];
        const float fr = wave_sum(hacc[r] * a1v);
        const float gr = wave_sum(hacc[r] * a2v);
        if (lane == 0) { fv[i0 + r] = fr; gv[i0 + r] = gr; }
    }
    __syncthreads();

    // hB[(row>>3)][feat][row&7]: thread f=tid>>2 handles feat f, cp=tid&3 the j8 sub-block
    const int f  = threadIdx.x >> 2;           // 0..63
    const int cp = threadIdx.x & 3;            // 0..3
    union { unsigned short s[8]; int4 v; } pk;
#pragma unroll
    for (int c = 0; c < 8; c++) pk.s[c] = (unsigned short)f2bf(hsm[cp * 8 + c][f]);
    *(int4*)&hB[(size_t)((blockRow0 >> 3) + cp) * 512 + f * 8] = pk.v;
}

// ---------- Main: fused masked-exp attention (MFMA) + den + LayerNorm + ELU ----------
// 16 rows/block, 256 thr (4 waves). Producer: wave w owns rows w*4..w*4+3, lane=column
// (fully coalesced adj). Consumer: wave w owns feature block w. grid = 512.
__global__ __launch_bounds__(256) void gat_attn(
    const int* __restrict__ adj, const unsigned short* __restrict__ hB,
    const float* __restrict__ fv, const float* __restrict__ gv,
    const float* __restrict__ gamma, const float* __restrict__ beta,
    float* __restrict__ out)
{
    __shared__ short wls[16][264];        // weight tile, row-major, pad 8 shorts
    __shared__ float lnbuf[16][68];
    __shared__ float denbuf[16];

    const int tid  = threadIdx.x;
    const int lane = tid & 63;
    const int wid  = tid >> 6;
    const int n16  = lane & 15;
    const int g4   = lane >> 4;
    const int rowBase = blockIdx.x * 16;
    const int rbase   = rowBase + wid * 4;    // producer rows of this wave

    float frow[4];
#pragma unroll
    for (int rr = 0; rr < 4; ++rr) frow[rr] = fv[rbase + rr];

    f32x4 acc = {0.f, 0.f, 0.f, 0.f};
    float dp[4] = {0.f, 0.f, 0.f, 0.f};

    i32x4  adjA[4], adjB[4];
    float4 gA, gB;

#define PREFETCH(JP, ADJ, G) do {                                              \
    _Pragma("unroll")                                                          \
    for (int rr = 0; rr < 4; ++rr)                                             \
        ADJ[rr] = __builtin_nontemporal_load(                                  \
            (const i32x4*)(adj + (size_t)(rbase + rr) * N + (JP) + lane * 4)); \
    G = *(const float4*)(gv + (JP) + lane * 4);                                \
} while (0)

#define STEP(C, ADJ, G, NADJ, NG) do {                                         \
    /* B fragments for chunk C -> regs (issued BEFORE next adj prefetch) */    \
    bf16x8 breg[8];                                                            \
    {                                                                          \
        const unsigned short* hb = hB + (size_t)((C) * 32 + g4) * 512          \
                                   + wid * 128 + n16 * 8;                      \
        _Pragma("unroll")                                                      \
        for (int ks = 0; ks < 8; ++ks)                                         \
            breg[ks] = *(const bf16x8*)(hb + (size_t)ks * 2048);               \
    }                                                                          \
    const int pc = ((C) + 1 < NCH) ? (C) + 1 : (C);                            \
    PREFETCH((size_t)pc * KVB, NADJ, NG);                                      \
    __syncthreads();  /* previous chunk's wls readers done */                  \
    _Pragma("unroll")                                                          \
    for (int rr = 0; rr < 4; ++rr) {                                           \
        s16x4 pk;                                                              \
        _Pragma("unroll")                                                      \
        for (int e = 0; e < 4; ++e) {                                          \
            float t = frow[rr] + ((const float*)&G)[e];                        \
            t = fmaxf(t, ALPHA * t);               /* leaky_relu */            \
            const float w = (((const int*)&ADJ[rr])[e] > 0) ? __expf(t) : 0.f; \
            const short wb = f2bf(w);                                          \
            dp[rr] += bf2f(wb);                                                \
            pk[e] = wb;                                                        \
        }                                                                      \
        *(s16x4*)&wls[wid * 4 + rr][lane * 4] = pk;                            \
    }                                                                          \
    __syncthreads();  /* wls visible */                                        \
    _Pragma("unroll")                                                          \
    for (int ks = 0; ks < 8; ++ks) {                                           \
        bf16x8 a = *(const bf16x8*)&wls[n16][ks * 32 + g4 * 8];                \
        acc = __builtin_amdgcn_mfma_f32_16x16x32_bf16(a, breg[ks], acc, 0, 0, 0); \
    }                                                                          \
} while (0)

    PREFETCH(0, adjA, gA);
    for (int c = 0; c < NCH; c += 2) {
        STEP(c,     adjA, gA, adjB, gB);
        STEP(c + 1, adjB, gB, adjA, gA);
    }
#undef STEP
#undef PREFETCH

    // ---- denominator: full-wave reduce per row slot ----
#pragma unroll
    for (int rr = 0; rr < 4; ++rr) {
        const float dr = wave_sum(dp[rr]);
        if (lane == 0) denbuf[wid * 4 + rr] = dr;
    }

    // ---- numerator: D frag -> lnbuf[row][feat] ----
#pragma unroll
    for (int r = 0; r < 4; ++r) lnbuf[g4 * 4 + r][wid * 16 + n16] = acc[r];
    __syncthreads();

    // ---- divide + LayerNorm + ELU: 16 threads per row ----
    const int r = tid >> 4;         // 0..15
    const int q = tid & 15;         // feature quad
    const float den = denbuf[r];
    float4 v = *(const float4*)&lnbuf[r][q * 4];
    const float inv = 1.0f / den;
    v.x *= inv; v.y *= inv; v.z *= inv; v.w *= inv;

    float sm = v.x + v.y + v.z + v.w;
#pragma unroll
    for (int o = 1; o < 16; o <<= 1) sm += __shfl_xor(sm, o, 64);
    const float mu = sm * (1.0f / 64.0f);

    const float dx = v.x - mu, dy = v.y - mu, dz = v.z - mu, dw = v.w - mu;
    float ss = dx * dx + dy * dy + dz * dz + dw * dw;
#pragma unroll
    for (int o = 1; o < 16; o <<= 1) ss += __shfl_xor(ss, o, 64);
    const float rs = rsqrtf(ss * (1.0f / 64.0f) + LN_EPS);

    const float4 gm = *(const float4*)&gamma[q * 4];
    const float4 bt = *(const float4*)&beta[q * 4];
    float y0 = dx * rs * gm.x + bt.x;
    float y1 = dy * rs * gm.y + bt.y;
    float y2 = dz * rs * gm.z + bt.z;
    float y3 = dw * rs * gm.w + bt.w;
    y0 = (y0 > 0.f) ? y0 : expm1f(y0);
    y1 = (y1 > 0.f) ? y1 : expm1f(y1);
    y2 = (y2 > 0.f) ? y2 : expm1f(y2);
    y3 = (y3 > 0.f) ? y3 : expm1f(y3);
    *(float4*)&out[(size_t)(rowBase + r) * OUT_F + q * 4] = make_float4(y0, y1, y2, y3);
}

extern "C" void kernel_launch(void* const* d_in, const int* in_sizes, int n_in,
                              void* d_out, int out_size, void* d_ws, size_t ws_size,
                              hipStream_t stream)
{
    const float* input = (const float*)d_in[0];
    const int*   adj   = (const int*)d_in[1];
    const float* W     = (const float*)d_in[2];
    const float* a1    = (const float*)d_in[3];
    const float* a2    = (const float*)d_in[4];
    const float* gamma = (const float*)d_in[5];
    const float* beta  = (const float*)d_in[6];
    float* out = (float*)d_out;

    // workspace: 1 MB hB + 32 KB f + 32 KB g
    unsigned short* hB = (unsigned short*)d_ws;
    float* fv = (float*)(hB + (size_t)OUT_F * N);
    float* gv = fv + N;

    gat_phaseA<<<N / 32, 256, 0, stream>>>(input, W, a1, a2, hB, fv, gv);
    gat_attn<<<N / 16, 256, 0, stream>>>(adj, hB, fv, gv, gamma, beta, out);
}